// Round 4
// baseline (595.109 us; speedup 1.0000x reference)
//
#include <hip/hip_runtime.h>

// CRF NLL forward loss. B=256, T=2048, K2=52 (50 labels + START=50 + STOP=51).
// Linear-domain bidirectional recurrence, FUSED INTO ONE WAVE per batch element:
//   fwd chain: v <- E_t * (M v),   t = 0..h-1      (h = L/2)
//   bwd chain: u <- M^T (E_t * u), t = L-1..h
//   score = ln2*(C + log2(sum u.*v))
//
// R10 change: R9 falsified the remat theory (asm-def M, VGPR still 52, dur
// flat). Counter re-read: VALUBusy 10% @ 2 waves/CU => each wave issues only
// ~128cyc/step of a ~640cyc step — the loop body is clean but LATENCY-BOUND:
// LDS write->read round trip (~250cyc) + emission-load HBM latency (4 in
// flight vs ~900cyc => ~225cyc/step). One chain cannot hide its own latency,
// so run BOTH independent chains (fwd+bwd of the same b) interleaved in one
// 64-lane wave: B's FMAs hide A's LDS/HBM waits. 8 emission loads in flight.
// Final dot is lane-local (vf*vb), no __syncthreads, 64-thread blocks.
// Renorm by a fixed always-positive component every 4 steps (growth < 2^95).

#define B_    256
#define T_    2048
#define K2_   52
#define LOG2E_ 1.4426950408889634f
#define LN2_   0.6931471805599453f

__device__ __forceinline__ int imin(int a, int b) { return a < b ? a : b; }
__device__ __forceinline__ int imax(int a, int b) { return a > b ? a : b; }

#define FORALL52(F) \
  F(0) F(1) F(2) F(3) F(4) F(5) F(6) F(7) F(8) F(9) F(10) F(11) F(12) F(13) \
  F(14) F(15) F(16) F(17) F(18) F(19) F(20) F(21) F(22) F(23) F(24) F(25) \
  F(26) F(27) F(28) F(29) F(30) F(31) F(32) F(33) F(34) F(35) F(36) F(37) \
  F(38) F(39) F(40) F(41) F(42) F(43) F(44) F(45) F(46) F(47) F(48) F(49) \
  F(50) F(51)

// M entries as opaque asm defs (kept from R9 — harmless, blocks remat).
// Forward: lane n holds row n of M (MF_i = exp(tr[n][i])).
// Backward: lane n holds col n of M (MB_i = exp(tr[i][n])).
#define DECLMF(i) float MF_##i; { float _t = tr[n * K2_ + i] * LOG2E_; \
  asm("v_exp_f32 %0, %1\n\ts_nop 1" : "=v"(MF_##i) : "v"(_t)); }
#define DECLMB(i) float MB_##i; { float _t = tr[i * K2_ + n] * LOG2E_; \
  asm("v_exp_f32 %0, %1\n\ts_nop 1" : "=v"(MB_##i) : "v"(_t)); }

#define ACCQF(Q, i0,i1,i2,i3) \
  _a0 = fmaf(MF_##i0, (Q).x, _a0); \
  _a1 = fmaf(MF_##i1, (Q).y, _a1); \
  _a2 = fmaf(MF_##i2, (Q).z, _a2); \
  _a3 = fmaf(MF_##i3, (Q).w, _a3);
#define ACCQB(Q, i0,i1,i2,i3) \
  _a0 = fmaf(MB_##i0, (Q).x, _a0); \
  _a1 = fmaf(MB_##i1, (Q).y, _a1); \
  _a2 = fmaf(MB_##i2, (Q).z, _a2); \
  _a3 = fmaf(MB_##i3, (Q).w, _a3);

// 8-deep streamed register rotation (peak 32 temp regs per chain).
// Forward matvec reads renorm group (48..51, comp 50 = .z) first.
#define MATVEC_F(OUTY, RENORMV) \
    const float4* _g4 = (const float4*)sF; \
    float4 _r0 = _g4[12], _r1 = _g4[0], _r2 = _g4[1], _r3 = _g4[2]; \
    float4 _r4 = _g4[3],  _r5 = _g4[4], _r6 = _g4[5], _r7 = _g4[6]; \
    float RENORMV = _r0.z; (void)RENORMV; \
    float _a0 = 0.0f, _a1 = 0.0f, _a2 = 0.0f, _a3 = 0.0f; \
    ACCQF(_r0,48,49,50,51)  _r0 = _g4[7]; \
    ACCQF(_r1, 0, 1, 2, 3)  _r1 = _g4[8]; \
    ACCQF(_r2, 4, 5, 6, 7)  _r2 = _g4[9]; \
    ACCQF(_r3, 8, 9,10,11)  _r3 = _g4[10]; \
    ACCQF(_r4,12,13,14,15)  _r4 = _g4[11]; \
    ACCQF(_r5,16,17,18,19) \
    ACCQF(_r6,20,21,22,23) \
    ACCQF(_r7,24,25,26,27) \
    ACCQF(_r0,28,29,30,31) \
    ACCQF(_r1,32,33,34,35) \
    ACCQF(_r2,36,37,38,39) \
    ACCQF(_r3,40,41,42,43) \
    ACCQF(_r4,44,45,46,47) \
    float OUTY = (_a0 + _a1) + (_a2 + _a3);

// Backward matvec reads renorm group (0..3, comp 0 = .x) first.
#define MATVEC_B(OUTY, RENORMV) \
    const float4* _g4 = (const float4*)sB; \
    float4 _r0 = _g4[0], _r1 = _g4[1], _r2 = _g4[2], _r3 = _g4[3]; \
    float4 _r4 = _g4[4], _r5 = _g4[5], _r6 = _g4[6], _r7 = _g4[7]; \
    float RENORMV = _r0.x; (void)RENORMV; \
    float _a0 = 0.0f, _a1 = 0.0f, _a2 = 0.0f, _a3 = 0.0f; \
    ACCQB(_r0, 0, 1, 2, 3)  _r0 = _g4[8]; \
    ACCQB(_r1, 4, 5, 6, 7)  _r1 = _g4[9]; \
    ACCQB(_r2, 8, 9,10,11)  _r2 = _g4[10]; \
    ACCQB(_r3,12,13,14,15)  _r3 = _g4[11]; \
    ACCQB(_r4,16,17,18,19)  _r4 = _g4[12]; \
    ACCQB(_r5,20,21,22,23) \
    ACCQB(_r6,24,25,26,27) \
    ACCQB(_r7,28,29,30,31) \
    ACCQB(_r0,32,33,34,35) \
    ACCQB(_r1,36,37,38,39) \
    ACCQB(_r2,40,41,42,43) \
    ACCQB(_r3,44,45,46,47) \
    ACCQB(_r4,48,49,50,51) \
    float OUTY = (_a0 + _a1) + (_a2 + _a3);

// ---- forward steps: v' = E_t * (M v); sF holds v. Renorm comp 50 (>0). ----
#define FSTEP_R(EV, NEWIDX) do {                                \
    float _ne  = emb[(size_t)(NEWIDX) * K2_ + n];               \
    MATVEC_F(_y, _m)                                            \
    float _inv = __builtin_amdgcn_rcpf(_m);                     \
    C += __builtin_amdgcn_logf(_m);                             \
    float _E = __builtin_amdgcn_exp2f((EV) * LOG2E_);           \
    vf = _y * (_inv * _E);                                      \
    sF[lane] = vf;                                              \
    EV = _ne;                                                   \
  } while (0)
#define FSTEP_N(EV, NEWIDX) do {                                \
    float _ne  = emb[(size_t)(NEWIDX) * K2_ + n];               \
    MATVEC_F(_y, _mu)                                           \
    float _E = __builtin_amdgcn_exp2f((EV) * LOG2E_);           \
    vf = _y * _E;                                               \
    sF[lane] = vf;                                              \
    EV = _ne;                                                   \
  } while (0)

// ---- backward steps: sB holds w = E .* u; step reads w, u' = M^T w, then
//      writes w' = u' * E_next (EV holds the NEXT step's emission). ----
#define BSTEP_R(EV, NEWIDX) do {                                \
    float _ne  = emb[(size_t)(NEWIDX) * K2_ + n];               \
    MATVEC_B(_y, _m)                                            \
    float _inv = __builtin_amdgcn_rcpf(_m);                     \
    C += __builtin_amdgcn_logf(_m);                             \
    vb = _y * _inv;                                             \
    float _E = __builtin_amdgcn_exp2f((EV) * LOG2E_);           \
    sB[lane] = vb * _E;                                         \
    EV = _ne;                                                   \
  } while (0)
#define BSTEP_N(EV, NEWIDX) do {                                \
    float _ne  = emb[(size_t)(NEWIDX) * K2_ + n];               \
    MATVEC_B(_y, _mu)                                           \
    vb = _y;                                                    \
    float _E = __builtin_amdgcn_exp2f((EV) * LOG2E_);           \
    sB[lane] = vb * _E;                                         \
    EV = _ne;                                                   \
  } while (0)

__launch_bounds__(64, 1)
__global__ void crf_fwd_kernel(const float* __restrict__ em,
                               const float* __restrict__ tr,
                               const int*  __restrict__ len,
                               const int*  __restrict__ lab,
                               float* __restrict__ per_b)
{
  const int b    = blockIdx.x;
  const int lane = threadIdx.x & 63;                 // 64 = 1 wave per block
  const int n    = (lane < K2_) ? lane : (K2_ - 1);  // lanes 52..63 mirror lane 51
  const int L    = len[b];
  const int h    = L >> 1;                           // fwd steps; bwd cnt = L-h
  const int cnt  = L - h;                            // cnt == h or h+1
  const float* emb = em + (size_t)b * (T_ * K2_);

  __shared__ __align__(16) float sF[64];   // fwd state vector (broadcast)
  __shared__ __align__(16) float sB[64];   // bwd state vector (broadcast)

  float C = 0.0f;

  // Both transition matrices resident in this wave's registers.
  FORALL52(DECLMF)
  FORALL52(DECLMB)

  // ---- fwd init ----
  float vf = (lane == 50) ? 1.0f : 0.0f;
  sF[lane] = vf;
  float f0 = emb[0 * K2_ + n];
  float f1 = emb[1 * K2_ + n];
  float f2 = emb[2 * K2_ + n];
  float f3 = emb[3 * K2_ + n];

  // ---- bwd init: u_0 = s (STOP row); w_0 = E_{L-1} .* u_0 ----
  float vb = __builtin_amdgcn_exp2f(tr[(K2_ - 1) * K2_ + n] * LOG2E_);
  float e0 = emb[(size_t)(L - 1) * K2_ + n];
  float bA = emb[(size_t)imax(L - 2, 0) * K2_ + n];
  float bB = emb[(size_t)imax(L - 3, 0) * K2_ + n];
  float bC = emb[(size_t)imax(L - 4, 0) * K2_ + n];
  float bD = emb[(size_t)imax(L - 5, 0) * K2_ + n];
  sB[lane] = vb * __builtin_amdgcn_exp2f(e0 * LOG2E_);

  // ---- interleaved main loop: 4 fwd + 4 bwd steps per iteration ----
  int t = 0;
  for (; t + 4 <= h; t += 4) {
    int i4 = imin(t + 4, T_ - 1), i5 = imin(t + 5, T_ - 1);
    int i6 = imin(t + 6, T_ - 1), i7 = imin(t + 7, T_ - 1);
    int j4 = imax(L - 6 - t, 0), j5 = imax(L - 7 - t, 0);
    int j6 = imax(L - 8 - t, 0), j7 = imax(L - 9 - t, 0);
    FSTEP_R(f0, i4);  BSTEP_R(bA, j4);
    FSTEP_N(f1, i5);  BSTEP_N(bB, j5);
    FSTEP_N(f2, i6);  BSTEP_N(bC, j6);
    FSTEP_N(f3, i7);  BSTEP_N(bD, j7);
  }
  int rem = h - t;                         // 0..3 remaining pairs
  if (rem > 0) { FSTEP_R(f0, T_ - 1); BSTEP_R(bA, 0); }
  if (rem > 1) { FSTEP_N(f1, T_ - 1); BSTEP_N(bB, 0); }
  if (rem > 2) { FSTEP_N(f2, T_ - 1); BSTEP_N(bC, 0); }
  if (cnt > h) {                           // one extra bwd step (L odd)
    if      (rem == 0) BSTEP_R(bA, 0);
    else if (rem == 1) BSTEP_N(bB, 0);
    else if (rem == 2) BSTEP_N(bC, 0);
    else               BSTEP_N(bD, 0);
  }

  // ---- gold score (whole wave, stride 64) ----
  float gold = 0.0f;
  const int* labb = lab + b * T_;
  for (int tt = lane; tt < L; tt += 64) {
    int l1 = labb[tt];
    int l0 = (tt == 0) ? 50 : labb[tt - 1];
    gold += emb[(size_t)tt * K2_ + l1] + tr[l1 * K2_ + l0];
  }
  if (lane == 0) gold += tr[(K2_ - 1) * K2_ + labb[L - 1]];  // STOP <- last label
#pragma unroll
  for (int off = 32; off >= 1; off >>= 1)
    gold += __shfl_xor(gold, off, 64);

  // ---- combine: dot(u, v) is lane-local now ----
  float x = (lane < K2_) ? vf * vb : 0.0f;
#pragma unroll
  for (int off = 32; off >= 1; off >>= 1)
    x += __shfl_xor(x, off, 64);
  if (lane == 0)
    per_b[b] = (C + __builtin_amdgcn_logf(x)) * LN2_ - gold;
}

__global__ void reduce_mean_kernel(const float* __restrict__ per_b,
                                   float* __restrict__ out)
{
  const int tid = threadIdx.x;  // 256
  float v = per_b[tid];
#pragma unroll
  for (int off = 32; off >= 1; off >>= 1) v += __shfl_xor(v, off, 64);
  __shared__ float s[4];
  if ((tid & 63) == 0) s[tid >> 6] = v;
  __syncthreads();
  if (tid == 0) out[0] = ((s[0] + s[1]) + (s[2] + s[3])) * (1.0f / (float)B_);
}

extern "C" void kernel_launch(void* const* d_in, const int* in_sizes, int n_in,
                              void* d_out, int out_size, void* d_ws, size_t ws_size,
                              hipStream_t stream) {
  const float* em  = (const float*)d_in[0];   // [B,T,K2] f32
  const float* tr  = (const float*)d_in[1];   // [K2,K2]  f32
  const int*   len = (const int*)d_in[2];     // [B] i32
  const int*   lab = (const int*)d_in[3];     // [B,T] i32
  float* out = (float*)d_out;
  float* ws  = (float*)d_ws;                  // 256 floats of per-batch scores

  crf_fwd_kernel<<<B_, 64, 0, stream>>>(em, tr, len, lab, ws);
  reduce_mean_kernel<<<1, 256, 0, stream>>>(ws, out);
}

// Round 5
// 568.751 us; speedup vs baseline: 1.0463x; 1.0463x over previous
//
#include <hip/hip_runtime.h>

// CRF NLL forward loss. B=256, T=2048, K2=52 (50 labels + START=50 + STOP=51).
// Linear-domain bidirectional recurrence, FUSED INTO ONE WAVE per batch element:
//   fwd chain: v <- E_t * (M v),   t = 0..h-1      (h = L/2)
//   bwd chain: u <- M^T (E_t * u), t = L-1..h
//   score = ln2*(C + log2(sum u.*v))
//
// R11 change: root cause of R7-R10 found in the VGPR_Count series (52 = 10-wave
// budget, 96 = ~5-wave budget): the AMDGPU scheduler targets a DEFAULT HIGH
// OCCUPANCY when sizing register pressure — __launch_bounds__(N,1) only sets
// the waves-per-eu MIN. It sank/remat'ed the (non-volatile, hence sinkable) M
// asm-defs into the loop to fit those budgets, even though this launch runs 1-2
// waves/CU. Fix: __attribute__((amdgpu_waves_per_eu(1,1))) — occupancy target
// 1 wave/EU, VGPR budget 512 — plus `asm volatile` M defs (unsinkable).
// Both 52-entry matrices (fwd rows + bwd cols) now stay truly resident.
// Renorm by a fixed always-positive component every 4 steps (growth < 2^95).

#define B_    256
#define T_    2048
#define K2_   52
#define LOG2E_ 1.4426950408889634f
#define LN2_   0.6931471805599453f

__device__ __forceinline__ int imin(int a, int b) { return a < b ? a : b; }
__device__ __forceinline__ int imax(int a, int b) { return a > b ? a : b; }

#define FORALL52(F) \
  F(0) F(1) F(2) F(3) F(4) F(5) F(6) F(7) F(8) F(9) F(10) F(11) F(12) F(13) \
  F(14) F(15) F(16) F(17) F(18) F(19) F(20) F(21) F(22) F(23) F(24) F(25) \
  F(26) F(27) F(28) F(29) F(30) F(31) F(32) F(33) F(34) F(35) F(36) F(37) \
  F(38) F(39) F(40) F(41) F(42) F(43) F(44) F(45) F(46) F(47) F(48) F(49) \
  F(50) F(51)

// M entries as VOLATILE asm defs: volatile inline asm cannot be sunk into the
// loop, duplicated, or deleted — the values must stay live in registers.
// Forward: lane n holds row n of M (MF_i = exp(tr[n][i])).
// Backward: lane n holds col n of M (MB_i = exp(tr[i][n])).
// s_nop 1 covers the trans-op -> VALU read wait state across the asm boundary.
#define DECLMF(i) float MF_##i; { float _t = tr[n * K2_ + i] * LOG2E_; \
  asm volatile("v_exp_f32 %0, %1\n\ts_nop 1" : "=v"(MF_##i) : "v"(_t)); }
#define DECLMB(i) float MB_##i; { float _t = tr[i * K2_ + n] * LOG2E_; \
  asm volatile("v_exp_f32 %0, %1\n\ts_nop 1" : "=v"(MB_##i) : "v"(_t)); }

#define ACCQF(Q, i0,i1,i2,i3) \
  _a0 = fmaf(MF_##i0, (Q).x, _a0); \
  _a1 = fmaf(MF_##i1, (Q).y, _a1); \
  _a2 = fmaf(MF_##i2, (Q).z, _a2); \
  _a3 = fmaf(MF_##i3, (Q).w, _a3);
#define ACCQB(Q, i0,i1,i2,i3) \
  _a0 = fmaf(MB_##i0, (Q).x, _a0); \
  _a1 = fmaf(MB_##i1, (Q).y, _a1); \
  _a2 = fmaf(MB_##i2, (Q).z, _a2); \
  _a3 = fmaf(MB_##i3, (Q).w, _a3);

// 8-deep streamed register rotation (peak 32 temp regs per chain).
// Forward matvec reads renorm group (48..51, comp 50 = .z) first.
#define MATVEC_F(OUTY, RENORMV) \
    const float4* _g4 = (const float4*)sF; \
    float4 _r0 = _g4[12], _r1 = _g4[0], _r2 = _g4[1], _r3 = _g4[2]; \
    float4 _r4 = _g4[3],  _r5 = _g4[4], _r6 = _g4[5], _r7 = _g4[6]; \
    float RENORMV = _r0.z; (void)RENORMV; \
    float _a0 = 0.0f, _a1 = 0.0f, _a2 = 0.0f, _a3 = 0.0f; \
    ACCQF(_r0,48,49,50,51)  _r0 = _g4[7]; \
    ACCQF(_r1, 0, 1, 2, 3)  _r1 = _g4[8]; \
    ACCQF(_r2, 4, 5, 6, 7)  _r2 = _g4[9]; \
    ACCQF(_r3, 8, 9,10,11)  _r3 = _g4[10]; \
    ACCQF(_r4,12,13,14,15)  _r4 = _g4[11]; \
    ACCQF(_r5,16,17,18,19) \
    ACCQF(_r6,20,21,22,23) \
    ACCQF(_r7,24,25,26,27) \
    ACCQF(_r0,28,29,30,31) \
    ACCQF(_r1,32,33,34,35) \
    ACCQF(_r2,36,37,38,39) \
    ACCQF(_r3,40,41,42,43) \
    ACCQF(_r4,44,45,46,47) \
    float OUTY = (_a0 + _a1) + (_a2 + _a3);

// Backward matvec reads renorm group (0..3, comp 0 = .x) first.
#define MATVEC_B(OUTY, RENORMV) \
    const float4* _g4 = (const float4*)sB; \
    float4 _r0 = _g4[0], _r1 = _g4[1], _r2 = _g4[2], _r3 = _g4[3]; \
    float4 _r4 = _g4[4], _r5 = _g4[5], _r6 = _g4[6], _r7 = _g4[7]; \
    float RENORMV = _r0.x; (void)RENORMV; \
    float _a0 = 0.0f, _a1 = 0.0f, _a2 = 0.0f, _a3 = 0.0f; \
    ACCQB(_r0, 0, 1, 2, 3)  _r0 = _g4[8]; \
    ACCQB(_r1, 4, 5, 6, 7)  _r1 = _g4[9]; \
    ACCQB(_r2, 8, 9,10,11)  _r2 = _g4[10]; \
    ACCQB(_r3,12,13,14,15)  _r3 = _g4[11]; \
    ACCQB(_r4,16,17,18,19)  _r4 = _g4[12]; \
    ACCQB(_r5,20,21,22,23) \
    ACCQB(_r6,24,25,26,27) \
    ACCQB(_r7,28,29,30,31) \
    ACCQB(_r0,32,33,34,35) \
    ACCQB(_r1,36,37,38,39) \
    ACCQB(_r2,40,41,42,43) \
    ACCQB(_r3,44,45,46,47) \
    ACCQB(_r4,48,49,50,51) \
    float OUTY = (_a0 + _a1) + (_a2 + _a3);

// ---- forward steps: v' = E_t * (M v); sF holds v. Renorm comp 50 (>0). ----
#define FSTEP_R(EV, NEWIDX) do {                                \
    float _ne  = emb[(size_t)(NEWIDX) * K2_ + n];               \
    MATVEC_F(_y, _m)                                            \
    float _inv = __builtin_amdgcn_rcpf(_m);                     \
    C += __builtin_amdgcn_logf(_m);                             \
    float _E = __builtin_amdgcn_exp2f((EV) * LOG2E_);           \
    vf = _y * (_inv * _E);                                      \
    sF[lane] = vf;                                              \
    EV = _ne;                                                   \
  } while (0)
#define FSTEP_N(EV, NEWIDX) do {                                \
    float _ne  = emb[(size_t)(NEWIDX) * K2_ + n];               \
    MATVEC_F(_y, _mu)                                           \
    float _E = __builtin_amdgcn_exp2f((EV) * LOG2E_);           \
    vf = _y * _E;                                               \
    sF[lane] = vf;                                              \
    EV = _ne;                                                   \
  } while (0)

// ---- backward steps: sB holds w = E .* u; step reads w, u' = M^T w, then
//      writes w' = u' * E_next (EV holds the NEXT step's emission). ----
#define BSTEP_R(EV, NEWIDX) do {                                \
    float _ne  = emb[(size_t)(NEWIDX) * K2_ + n];               \
    MATVEC_B(_y, _m)                                            \
    float _inv = __builtin_amdgcn_rcpf(_m);                     \
    C += __builtin_amdgcn_logf(_m);                             \
    vb = _y * _inv;                                             \
    float _E = __builtin_amdgcn_exp2f((EV) * LOG2E_);           \
    sB[lane] = vb * _E;                                         \
    EV = _ne;                                                   \
  } while (0)
#define BSTEP_N(EV, NEWIDX) do {                                \
    float _ne  = emb[(size_t)(NEWIDX) * K2_ + n];               \
    MATVEC_B(_y, _mu)                                           \
    vb = _y;                                                    \
    float _E = __builtin_amdgcn_exp2f((EV) * LOG2E_);           \
    sB[lane] = vb * _E;                                         \
    EV = _ne;                                                   \
  } while (0)

__global__ __launch_bounds__(64)
__attribute__((amdgpu_waves_per_eu(1, 1)))
void crf_fwd_kernel(const float* __restrict__ em,
                    const float* __restrict__ tr,
                    const int*  __restrict__ len,
                    const int*  __restrict__ lab,
                    float* __restrict__ per_b)
{
  const int b    = blockIdx.x;
  const int lane = threadIdx.x & 63;                 // 64 = 1 wave per block
  const int n    = (lane < K2_) ? lane : (K2_ - 1);  // lanes 52..63 mirror lane 51
  const int L    = len[b];
  const int h    = L >> 1;                           // fwd steps; bwd cnt = L-h
  const int cnt  = L - h;                            // cnt == h or h+1
  const float* emb = em + (size_t)b * (T_ * K2_);

  __shared__ __align__(16) float sF[64];   // fwd state vector (broadcast)
  __shared__ __align__(16) float sB[64];   // bwd state vector (broadcast)

  float C = 0.0f;

  // Both transition matrices resident in this wave's registers.
  FORALL52(DECLMF)
  FORALL52(DECLMB)

  // ---- fwd init ----
  float vf = (lane == 50) ? 1.0f : 0.0f;
  sF[lane] = vf;
  float f0 = emb[0 * K2_ + n];
  float f1 = emb[1 * K2_ + n];
  float f2 = emb[2 * K2_ + n];
  float f3 = emb[3 * K2_ + n];

  // ---- bwd init: u_0 = s (STOP row); w_0 = E_{L-1} .* u_0 ----
  float vb = __builtin_amdgcn_exp2f(tr[(K2_ - 1) * K2_ + n] * LOG2E_);
  float e0 = emb[(size_t)(L - 1) * K2_ + n];
  float bA = emb[(size_t)imax(L - 2, 0) * K2_ + n];
  float bB = emb[(size_t)imax(L - 3, 0) * K2_ + n];
  float bC = emb[(size_t)imax(L - 4, 0) * K2_ + n];
  float bD = emb[(size_t)imax(L - 5, 0) * K2_ + n];
  sB[lane] = vb * __builtin_amdgcn_exp2f(e0 * LOG2E_);

  // ---- interleaved main loop: 4 fwd + 4 bwd steps per iteration ----
  int t = 0;
  for (; t + 4 <= h; t += 4) {
    int i4 = imin(t + 4, T_ - 1), i5 = imin(t + 5, T_ - 1);
    int i6 = imin(t + 6, T_ - 1), i7 = imin(t + 7, T_ - 1);
    int j4 = imax(L - 6 - t, 0), j5 = imax(L - 7 - t, 0);
    int j6 = imax(L - 8 - t, 0), j7 = imax(L - 9 - t, 0);
    FSTEP_R(f0, i4);  BSTEP_R(bA, j4);
    FSTEP_N(f1, i5);  BSTEP_N(bB, j5);
    FSTEP_N(f2, i6);  BSTEP_N(bC, j6);
    FSTEP_N(f3, i7);  BSTEP_N(bD, j7);
  }
  int rem = h - t;                         // 0..3 remaining pairs
  if (rem > 0) { FSTEP_R(f0, T_ - 1); BSTEP_R(bA, 0); }
  if (rem > 1) { FSTEP_N(f1, T_ - 1); BSTEP_N(bB, 0); }
  if (rem > 2) { FSTEP_N(f2, T_ - 1); BSTEP_N(bC, 0); }
  if (cnt > h) {                           // one extra bwd step (L odd)
    if      (rem == 0) BSTEP_R(bA, 0);
    else if (rem == 1) BSTEP_N(bB, 0);
    else if (rem == 2) BSTEP_N(bC, 0);
    else               BSTEP_N(bD, 0);
  }

  // ---- gold score (whole wave, stride 64) ----
  float gold = 0.0f;
  const int* labb = lab + b * T_;
  for (int tt = lane; tt < L; tt += 64) {
    int l1 = labb[tt];
    int l0 = (tt == 0) ? 50 : labb[tt - 1];
    gold += emb[(size_t)tt * K2_ + l1] + tr[l1 * K2_ + l0];
  }
  if (lane == 0) gold += tr[(K2_ - 1) * K2_ + labb[L - 1]];  // STOP <- last label
#pragma unroll
  for (int off = 32; off >= 1; off >>= 1)
    gold += __shfl_xor(gold, off, 64);

  // ---- combine: dot(u, v) is lane-local now ----
  float x = (lane < K2_) ? vf * vb : 0.0f;
#pragma unroll
  for (int off = 32; off >= 1; off >>= 1)
    x += __shfl_xor(x, off, 64);
  if (lane == 0)
    per_b[b] = (C + __builtin_amdgcn_logf(x)) * LN2_ - gold;
}

__global__ void reduce_mean_kernel(const float* __restrict__ per_b,
                                   float* __restrict__ out)
{
  const int tid = threadIdx.x;  // 256
  float v = per_b[tid];
#pragma unroll
  for (int off = 32; off >= 1; off >>= 1) v += __shfl_xor(v, off, 64);
  __shared__ float s[4];
  if ((tid & 63) == 0) s[tid >> 6] = v;
  __syncthreads();
  if (tid == 0) out[0] = ((s[0] + s[1]) + (s[2] + s[3])) * (1.0f / (float)B_);
}

extern "C" void kernel_launch(void* const* d_in, const int* in_sizes, int n_in,
                              void* d_out, int out_size, void* d_ws, size_t ws_size,
                              hipStream_t stream) {
  const float* em  = (const float*)d_in[0];   // [B,T,K2] f32
  const float* tr  = (const float*)d_in[1];   // [K2,K2]  f32
  const int*   len = (const int*)d_in[2];     // [B] i32
  const int*   lab = (const int*)d_in[3];     // [B,T] i32
  float* out = (float*)d_out;
  float* ws  = (float*)d_ws;                  // 256 floats of per-batch scores

  crf_fwd_kernel<<<B_, 64, 0, stream>>>(em, tr, len, lab, ws);
  reduce_mean_kernel<<<1, 256, 0, stream>>>(ws, out);
}

// Round 7
// 529.591 us; speedup vs baseline: 1.1237x; 1.0739x over previous
//
#include <hip/hip_runtime.h>

// CRF NLL forward loss. B=256, T=2048, K2=52 (50 labels + START=50 + STOP=51).
// Linear-domain bidirectional recurrence:
//   fwd: v <- E_t * (M v), t=0..h-1   bwd: u <- M^T (E_t * u), t=L-1..h
//   score = ln2*(Cf + Cb + log2(dot(u,v)))
//
// R13 = R12 resubmit (R12 bench was an infra failure: container died twice;
// no compile/correctness signal). Design rationale:
// The chain step is DEP-LATENCY bound (~640cyc: LDS write->read turnaround
// + b128 read stream + 13-deep FMA chain + epilogue; issue only ~130). One
// chain/wave can't beat its own latency (R7's waves sit on separate SIMDs).
// R10 proved two chains in ONE wave overlap dep chains (~600cyc saved/pair) but
// used the slow rotation body and needed both M and M^T (104 regs -> allocator
// sabotage). Fix: pair SAME-DIRECTION chains of TWO BATCHES per wave — M shared
// (52 regs). Block = 2 waves: wave0 fwd(pA)+fwd(pB), wave1 bwd(pA)+bwd(pB).
// A tiny bitonic sort pairs batches by length (any permutation is correct; the
// sort only equalizes chain lengths so the solo tails are short). Micro: 8
// accumulators (FMA dep 13->7), emission exp2 hoisted to quad top, 13-upfront
// b128 reads (R7's proven body). waves_per_eu(1,1) + volatile asm M defs keep
// M resident. Renorm every 4 steps per chain.

#define B_    256
#define T_    2048
#define K2_   52
#define LOG2E_ 1.4426950408889634f
#define LN2_   0.6931471805599453f

__device__ __forceinline__ int imin(int a, int b) { return a < b ? a : b; }
__device__ __forceinline__ int imax(int a, int b) { return a > b ? a : b; }

#define X2F(e) __builtin_amdgcn_exp2f((e) * LOG2E_)

#define FORALL52(F) \
  F(0) F(1) F(2) F(3) F(4) F(5) F(6) F(7) F(8) F(9) F(10) F(11) F(12) F(13) \
  F(14) F(15) F(16) F(17) F(18) F(19) F(20) F(21) F(22) F(23) F(24) F(25) \
  F(26) F(27) F(28) F(29) F(30) F(31) F(32) F(33) F(34) F(35) F(36) F(37) \
  F(38) F(39) F(40) F(41) F(42) F(43) F(44) F(45) F(46) F(47) F(48) F(49) \
  F(50) F(51)

// M defs: volatile asm (unsinkable/undupable) so the 52 values stay resident.
// Forward: lane n holds row n (MF_i = exp(tr[n][i])). Backward: col n.
#define DECLMF(i) float MF_##i; { float _t = tr[n * K2_ + i] * LOG2E_; \
  asm volatile("v_exp_f32 %0, %1\n\ts_nop 1" : "=v"(MF_##i) : "v"(_t)); }
#define DECLMB(i) float MB_##i; { float _t = tr[i * K2_ + n] * LOG2E_; \
  asm volatile("v_exp_f32 %0, %1\n\ts_nop 1" : "=v"(MB_##i) : "v"(_t)); }

// ---- 13-upfront float4 broadcast reads -------------------------------------
#define READ13F(P, SH) \
  const float4* P##g = (const float4*)(SH); \
  float4 P##qc = P##g[12]; \
  float4 P##q0 = P##g[0],  P##q1 = P##g[1],  P##q2  = P##g[2],  P##q3  = P##g[3]; \
  float4 P##q4 = P##g[4],  P##q5 = P##g[5],  P##q6  = P##g[6],  P##q7  = P##g[7]; \
  float4 P##q8 = P##g[8],  P##q9 = P##g[9],  P##q10 = P##g[10], P##q11 = P##g[11];

#define READ13B(P, SH) \
  const float4* P##g = (const float4*)(SH); \
  float4 P##q0 = P##g[0],  P##q1 = P##g[1],  P##q2  = P##g[2],  P##q3  = P##g[3]; \
  float4 P##q4 = P##g[4],  P##q5 = P##g[5],  P##q6  = P##g[6],  P##q7  = P##g[7]; \
  float4 P##q8 = P##g[8],  P##q9 = P##g[9],  P##q10 = P##g[10], P##q11 = P##g[11]; \
  float4 P##qc = P##g[12];

#define ACCQ4(MP, Q, i0,i1,i2,i3, A0,A1,A2,A3) \
  A0 = fmaf(MP##_##i0, (Q).x, A0); \
  A1 = fmaf(MP##_##i1, (Q).y, A1); \
  A2 = fmaf(MP##_##i2, (Q).z, A2); \
  A3 = fmaf(MP##_##i3, (Q).w, A3);

// 52 FMAs into 8 accumulators (two quad-sets alternate -> dep depth 7).
#define ACC52F(P) \
  float P##s0=0.f,P##s1=0.f,P##s2=0.f,P##s3=0.f; \
  float P##s4=0.f,P##s5=0.f,P##s6=0.f,P##s7=0.f; \
  ACCQ4(MF, P##qc, 48,49,50,51, P##s0,P##s1,P##s2,P##s3) \
  ACCQ4(MF, P##q0,  0, 1, 2, 3, P##s4,P##s5,P##s6,P##s7) \
  ACCQ4(MF, P##q1,  4, 5, 6, 7, P##s0,P##s1,P##s2,P##s3) \
  ACCQ4(MF, P##q2,  8, 9,10,11, P##s4,P##s5,P##s6,P##s7) \
  ACCQ4(MF, P##q3, 12,13,14,15, P##s0,P##s1,P##s2,P##s3) \
  ACCQ4(MF, P##q4, 16,17,18,19, P##s4,P##s5,P##s6,P##s7) \
  ACCQ4(MF, P##q5, 20,21,22,23, P##s0,P##s1,P##s2,P##s3) \
  ACCQ4(MF, P##q6, 24,25,26,27, P##s4,P##s5,P##s6,P##s7) \
  ACCQ4(MF, P##q7, 28,29,30,31, P##s0,P##s1,P##s2,P##s3) \
  ACCQ4(MF, P##q8, 32,33,34,35, P##s4,P##s5,P##s6,P##s7) \
  ACCQ4(MF, P##q9, 36,37,38,39, P##s0,P##s1,P##s2,P##s3) \
  ACCQ4(MF, P##q10,40,41,42,43, P##s4,P##s5,P##s6,P##s7) \
  ACCQ4(MF, P##q11,44,45,46,47, P##s0,P##s1,P##s2,P##s3) \
  float P##y = ((P##s0+P##s1)+(P##s2+P##s3)) + ((P##s4+P##s5)+(P##s6+P##s7));

#define ACC52B(P) \
  float P##s0=0.f,P##s1=0.f,P##s2=0.f,P##s3=0.f; \
  float P##s4=0.f,P##s5=0.f,P##s6=0.f,P##s7=0.f; \
  ACCQ4(MB, P##q0,  0, 1, 2, 3, P##s0,P##s1,P##s2,P##s3) \
  ACCQ4(MB, P##q1,  4, 5, 6, 7, P##s4,P##s5,P##s6,P##s7) \
  ACCQ4(MB, P##q2,  8, 9,10,11, P##s0,P##s1,P##s2,P##s3) \
  ACCQ4(MB, P##q3, 12,13,14,15, P##s4,P##s5,P##s6,P##s7) \
  ACCQ4(MB, P##q4, 16,17,18,19, P##s0,P##s1,P##s2,P##s3) \
  ACCQ4(MB, P##q5, 20,21,22,23, P##s4,P##s5,P##s6,P##s7) \
  ACCQ4(MB, P##q6, 24,25,26,27, P##s0,P##s1,P##s2,P##s3) \
  ACCQ4(MB, P##q7, 28,29,30,31, P##s4,P##s5,P##s6,P##s7) \
  ACCQ4(MB, P##q8, 32,33,34,35, P##s0,P##s1,P##s2,P##s3) \
  ACCQ4(MB, P##q9, 36,37,38,39, P##s4,P##s5,P##s6,P##s7) \
  ACCQ4(MB, P##q10,40,41,42,43, P##s0,P##s1,P##s2,P##s3) \
  ACCQ4(MB, P##q11,44,45,46,47, P##s4,P##s5,P##s6,P##s7) \
  ACCQ4(MB, P##qc, 48,49,50,51, P##s0,P##s1,P##s2,P##s3) \
  float P##y = ((P##s0+P##s1)+(P##s2+P##s3)) + ((P##s4+P##s5)+(P##s6+P##s7));

// ---- paired fwd steps: both chains' reads first, then compute A, then B ----
#define FSTEP2_R(EVA, NIA, EA, EVB, NIB, EB) do {                 \
    float _neA = embA[(size_t)(NIA) * K2_ + n];                   \
    float _neB = embB[(size_t)(NIB) * K2_ + n];                   \
    READ13F(A, sF0)                                               \
    READ13F(B, sF1)                                               \
    ACC52F(A)                                                     \
    { float _m = Aqc.z;                                           \
      CfA += __builtin_amdgcn_logf(_m);                           \
      vfA = Ay * (__builtin_amdgcn_rcpf(_m) * (EA));              \
      sF0[lane] = vfA; }                                          \
    EVA = _neA;                                                   \
    ACC52F(B)                                                     \
    { float _m = Bqc.z;                                           \
      CfB += __builtin_amdgcn_logf(_m);                           \
      vfB = By * (__builtin_amdgcn_rcpf(_m) * (EB));              \
      sF1[lane] = vfB; }                                          \
    EVB = _neB;                                                   \
  } while (0)

#define FSTEP2_N(EVA, NIA, EA, EVB, NIB, EB) do {                 \
    float _neA = embA[(size_t)(NIA) * K2_ + n];                   \
    float _neB = embB[(size_t)(NIB) * K2_ + n];                   \
    READ13F(A, sF0)                                               \
    READ13F(B, sF1)                                               \
    ACC52F(A)                                                     \
    vfA = Ay * (EA); sF0[lane] = vfA; EVA = _neA;                 \
    ACC52F(B)                                                     \
    vfB = By * (EB); sF1[lane] = vfB; EVB = _neB;                 \
  } while (0)

// ---- paired bwd steps: LDS holds w = E.*u; u' = M^T w; write w' = u'*E_next -
#define BSTEP2_R(EVA, NIA, EA, EVB, NIB, EB) do {                 \
    float _neA = embA[(size_t)(NIA) * K2_ + n];                   \
    float _neB = embB[(size_t)(NIB) * K2_ + n];                   \
    READ13B(A, sB0)                                               \
    READ13B(B, sB1)                                               \
    ACC52B(A)                                                     \
    { float _m = Aq0.x;                                           \
      CbA += __builtin_amdgcn_logf(_m);                           \
      vbA = Ay * __builtin_amdgcn_rcpf(_m);                       \
      sB0[lane] = vbA * (EA); }                                   \
    EVA = _neA;                                                   \
    ACC52B(B)                                                     \
    { float _m = Bq0.x;                                           \
      CbB += __builtin_amdgcn_logf(_m);                           \
      vbB = By * __builtin_amdgcn_rcpf(_m);                       \
      sB1[lane] = vbB * (EB); }                                   \
    EVB = _neB;                                                   \
  } while (0)

#define BSTEP2_N(EVA, NIA, EA, EVB, NIB, EB) do {                 \
    float _neA = embA[(size_t)(NIA) * K2_ + n];                   \
    float _neB = embB[(size_t)(NIB) * K2_ + n];                   \
    READ13B(A, sB0)                                               \
    READ13B(B, sB1)                                               \
    ACC52B(A)                                                     \
    vbA = Ay; sB0[lane] = vbA * (EA); EVA = _neA;                 \
    ACC52B(B)                                                     \
    vbB = By; sB1[lane] = vbB * (EB); EVB = _neB;                 \
  } while (0)

// ---- solo steps for the (short, sorted) tails ------------------------------
#define FSOLO_R(SH, VV, CC, EV, NI, EMB) do {                     \
    float _ne = EMB[(size_t)(NI) * K2_ + n];                      \
    READ13F(S, SH)                                                \
    ACC52F(S)                                                     \
    float _m = Sqc.z;                                             \
    CC += __builtin_amdgcn_logf(_m);                              \
    VV = Sy * (__builtin_amdgcn_rcpf(_m) * X2F(EV));              \
    SH[lane] = VV; EV = _ne;                                      \
  } while (0)
#define FSOLO_N(SH, VV, EV, NI, EMB) do {                         \
    float _ne = EMB[(size_t)(NI) * K2_ + n];                      \
    READ13F(S, SH)                                                \
    ACC52F(S)                                                     \
    VV = Sy * X2F(EV);                                            \
    SH[lane] = VV; EV = _ne;                                      \
  } while (0)
#define BSOLO_R(SH, VV, CC, EV, NI, EMB) do {                     \
    float _ne = EMB[(size_t)(NI) * K2_ + n];                      \
    READ13B(S, SH)                                                \
    ACC52B(S)                                                     \
    float _m = Sq0.x;                                             \
    CC += __builtin_amdgcn_logf(_m);                              \
    VV = Sy * __builtin_amdgcn_rcpf(_m);                          \
    SH[lane] = VV * X2F(EV); EV = _ne;                            \
  } while (0)
#define BSOLO_N(SH, VV, EV, NI, EMB) do {                         \
    float _ne = EMB[(size_t)(NI) * K2_ + n];                      \
    READ13B(S, SH)                                                \
    ACC52B(S)                                                     \
    VV = Sy;                                                      \
    SH[lane] = VV * X2F(EV); EV = _ne;                            \
  } while (0)

// ---- length-sort: pairs batches of near-equal length (any perm is correct) --
__global__ void pair_kernel(const int* __restrict__ len, int* __restrict__ perm)
{
  __shared__ int sk[256], sv[256];
  const int tid = threadIdx.x;
  sk[tid] = len[tid]; sv[tid] = tid;
  __syncthreads();
  for (int size = 2; size <= 256; size <<= 1) {
    for (int j = size >> 1; j > 0; j >>= 1) {
      int ixj = tid ^ j;
      if (ixj > tid) {
        int a = sk[tid], b2 = sk[ixj];
        bool up = ((tid & size) == 0);
        if (up ? (a > b2) : (a < b2)) {
          sk[tid] = b2; sk[ixj] = a;
          int tv = sv[tid]; sv[tid] = sv[ixj]; sv[ixj] = tv;
        }
      }
      __syncthreads();
    }
  }
  perm[tid] = sv[tid];
}

__global__ __launch_bounds__(128)
__attribute__((amdgpu_waves_per_eu(1, 1)))
void crf_fwd_kernel(const float* __restrict__ em,
                    const float* __restrict__ tr,
                    const int*  __restrict__ len,
                    const int*  __restrict__ lab,
                    const int*  __restrict__ perm,
                    float* __restrict__ per_b)
{
  const int tid  = threadIdx.x;                      // 128 = 2 waves
  const int wave = tid >> 6;
  const int lane = tid & 63;
  const int n    = (lane < K2_) ? lane : (K2_ - 1);  // lanes 52..63 mirror 51
  const int pA   = perm[2 * blockIdx.x];
  const int pB   = perm[2 * blockIdx.x + 1];
  const int LA   = len[pA], LB = len[pB];
  const int hA   = LA >> 1, hB = LB >> 1;
  const float* embA = em + (size_t)pA * (T_ * K2_);
  const float* embB = em + (size_t)pB * (T_ * K2_);

  __shared__ __align__(16) float sF0[64], sF1[64];   // fwd states (A, B)
  __shared__ __align__(16) float sB0[64], sB1[64];   // bwd states (A, B)
  __shared__ float sC[2];                            // bwd log-offsets
  __shared__ float sG[2];                            // gold partials

  float vfA = 0.f, vfB = 0.f, CfA = 0.f, CfB = 0.f;  // live into combine

  if (wave == 0) {
    // ================= forward chains of pA and pB ==========================
    FORALL52(DECLMF)
    vfA = (lane == 50) ? 1.0f : 0.0f;
    vfB = vfA;
    sF0[lane] = vfA; sF1[lane] = vfB;
    float fA0 = embA[0 * K2_ + n], fA1 = embA[1 * K2_ + n];
    float fA2 = embA[2 * K2_ + n], fA3 = embA[3 * K2_ + n];
    float fB0 = embB[0 * K2_ + n], fB1 = embB[1 * K2_ + n];
    float fB2 = embB[2 * K2_ + n], fB3 = embB[3 * K2_ + n];

    const int mn = imin(hA, hB);
    int t = 0;
    for (; t + 4 <= mn; t += 4) {
      float EA0 = X2F(fA0), EA1 = X2F(fA1), EA2 = X2F(fA2), EA3 = X2F(fA3);
      float EB0 = X2F(fB0), EB1 = X2F(fB1), EB2 = X2F(fB2), EB3 = X2F(fB3);
      int iA4 = imin(t + 4, T_ - 1), iA5 = imin(t + 5, T_ - 1);
      int iA6 = imin(t + 6, T_ - 1), iA7 = imin(t + 7, T_ - 1);
      FSTEP2_R(fA0, iA4, EA0, fB0, iA4, EB0);
      FSTEP2_N(fA1, iA5, EA1, fB1, iA5, EB1);
      FSTEP2_N(fA2, iA6, EA2, fB2, iA6, EB2);
      FSTEP2_N(fA3, iA7, EA3, fB3, iA7, EB3);
    }
    // ---- solo tails (short after length-sort) ----
    int tA = t;
    while (tA + 4 <= hA) {
      FSOLO_R(sF0, vfA, CfA, fA0, imin(tA + 4, T_ - 1), embA);
      FSOLO_N(sF0, vfA,      fA1, imin(tA + 5, T_ - 1), embA);
      FSOLO_N(sF0, vfA,      fA2, imin(tA + 6, T_ - 1), embA);
      FSOLO_N(sF0, vfA,      fA3, imin(tA + 7, T_ - 1), embA);
      tA += 4;
    }
    int remA = hA - tA;
    if (remA > 0) FSOLO_R(sF0, vfA, CfA, fA0, T_ - 1, embA);
    if (remA > 1) FSOLO_N(sF0, vfA,      fA1, T_ - 1, embA);
    if (remA > 2) FSOLO_N(sF0, vfA,      fA2, T_ - 1, embA);
    int tB = t;
    while (tB + 4 <= hB) {
      FSOLO_R(sF1, vfB, CfB, fB0, imin(tB + 4, T_ - 1), embB);
      FSOLO_N(sF1, vfB,      fB1, imin(tB + 5, T_ - 1), embB);
      FSOLO_N(sF1, vfB,      fB2, imin(tB + 6, T_ - 1), embB);
      FSOLO_N(sF1, vfB,      fB3, imin(tB + 7, T_ - 1), embB);
      tB += 4;
    }
    int remB = hB - tB;
    if (remB > 0) FSOLO_R(sF1, vfB, CfB, fB0, T_ - 1, embB);
    if (remB > 1) FSOLO_N(sF1, vfB,      fB1, T_ - 1, embB);
    if (remB > 2) FSOLO_N(sF1, vfB,      fB2, T_ - 1, embB);
  } else {
    // ================= backward chains of pA and pB =========================
    FORALL52(DECLMB)
    float vbA, vbB, CbA = 0.f, CbB = 0.f;
    vbA = __builtin_amdgcn_exp2f(tr[(K2_ - 1) * K2_ + n] * LOG2E_);
    vbB = vbA;
    const int cA = LA - hA, cB = LB - hB;
    float eA0 = embA[(size_t)(LA - 1) * K2_ + n];
    float eB0 = embB[(size_t)(LB - 1) * K2_ + n];
    float bA0 = embA[(size_t)imax(LA - 2, 0) * K2_ + n];
    float bA1 = embA[(size_t)imax(LA - 3, 0) * K2_ + n];
    float bA2 = embA[(size_t)imax(LA - 4, 0) * K2_ + n];
    float bA3 = embA[(size_t)imax(LA - 5, 0) * K2_ + n];
    float bB0 = embB[(size_t)imax(LB - 2, 0) * K2_ + n];
    float bB1 = embB[(size_t)imax(LB - 3, 0) * K2_ + n];
    float bB2 = embB[(size_t)imax(LB - 4, 0) * K2_ + n];
    float bB3 = embB[(size_t)imax(LB - 5, 0) * K2_ + n];
    sB0[lane] = vbA * X2F(eA0);   // w_0 = E_{L-1} .* u_0
    sB1[lane] = vbB * X2F(eB0);

    const int mc = imin(cA, cB);
    int s = 0;
    for (; s + 4 <= mc; s += 4) {
      float EA0 = X2F(bA0), EA1 = X2F(bA1), EA2 = X2F(bA2), EA3 = X2F(bA3);
      float EB0 = X2F(bB0), EB1 = X2F(bB1), EB2 = X2F(bB2), EB3 = X2F(bB3);
      int jA4 = imax(LA - 6 - s, 0), jA5 = imax(LA - 7 - s, 0);
      int jA6 = imax(LA - 8 - s, 0), jA7 = imax(LA - 9 - s, 0);
      int jB4 = imax(LB - 6 - s, 0), jB5 = imax(LB - 7 - s, 0);
      int jB6 = imax(LB - 8 - s, 0), jB7 = imax(LB - 9 - s, 0);
      BSTEP2_R(bA0, jA4, EA0, bB0, jB4, EB0);
      BSTEP2_N(bA1, jA5, EA1, bB1, jB5, EB1);
      BSTEP2_N(bA2, jA6, EA2, bB2, jB6, EB2);
      BSTEP2_N(bA3, jA7, EA3, bB3, jB7, EB3);
    }
    // ---- solo tails ----
    int sA = s;
    while (sA + 4 <= cA) {
      BSOLO_R(sB0, vbA, CbA, bA0, imax(LA - 6 - sA, 0), embA);
      BSOLO_N(sB0, vbA,      bA1, imax(LA - 7 - sA, 0), embA);
      BSOLO_N(sB0, vbA,      bA2, imax(LA - 8 - sA, 0), embA);
      BSOLO_N(sB0, vbA,      bA3, imax(LA - 9 - sA, 0), embA);
      sA += 4;
    }
    int remA = cA - sA;
    if (remA > 0) BSOLO_R(sB0, vbA, CbA, bA0, 0, embA);
    if (remA > 1) BSOLO_N(sB0, vbA,      bA1, 0, embA);
    if (remA > 2) BSOLO_N(sB0, vbA,      bA2, 0, embA);
    int sB_ = s;
    while (sB_ + 4 <= cB) {
      BSOLO_R(sB1, vbB, CbB, bB0, imax(LB - 6 - sB_, 0), embB);
      BSOLO_N(sB1, vbB,      bB1, imax(LB - 7 - sB_, 0), embB);
      BSOLO_N(sB1, vbB,      bB2, imax(LB - 8 - sB_, 0), embB);
      BSOLO_N(sB1, vbB,      bB3, imax(LB - 9 - sB_, 0), embB);
      sB_ += 4;
    }
    int remB = cB - sB_;
    if (remB > 0) BSOLO_R(sB1, vbB, CbB, bB0, 0, embB);
    if (remB > 1) BSOLO_N(sB1, vbB,      bB1, 0, embB);
    if (remB > 2) BSOLO_N(sB1, vbB,      bB2, 0, embB);

    sB0[lane] = vbA;              // publish final u vectors
    sB1[lane] = vbB;
    if (lane == 0) { sC[0] = CbA; sC[1] = CbB; }
  }

  // ---- gold score: wave0 -> pA, wave1 -> pB (stride 64) ----
  {
    const int    pg   = (wave == 0) ? pA : pB;
    const int    Lg   = (wave == 0) ? LA : LB;
    const float* embG = (wave == 0) ? embA : embB;
    const int*   labb = lab + pg * T_;
    float gold = 0.0f;
    for (int tt = lane; tt < Lg; tt += 64) {
      int l1 = labb[tt];
      int l0 = (tt == 0) ? 50 : labb[tt - 1];
      gold += embG[(size_t)tt * K2_ + l1] + tr[l1 * K2_ + l0];
    }
    if (lane == 0) gold += tr[(K2_ - 1) * K2_ + labb[Lg - 1]];  // STOP <- last
#pragma unroll
    for (int off = 32; off >= 1; off >>= 1)
      gold += __shfl_xor(gold, off, 64);
    if (lane == 0) sG[wave] = gold;
  }

  __syncthreads();

  if (wave == 0) {
    float xA = (lane < K2_) ? vfA * sB0[lane] : 0.0f;
    float xB = (lane < K2_) ? vfB * sB1[lane] : 0.0f;
#pragma unroll
    for (int off = 32; off >= 1; off >>= 1) {
      xA += __shfl_xor(xA, off, 64);
      xB += __shfl_xor(xB, off, 64);
    }
    if (lane == 0) {
      per_b[pA] = (CfA + sC[0] + __builtin_amdgcn_logf(xA)) * LN2_ - sG[0];
      per_b[pB] = (CfB + sC[1] + __builtin_amdgcn_logf(xB)) * LN2_ - sG[1];
    }
  }
}

__global__ void reduce_mean_kernel(const float* __restrict__ per_b,
                                   float* __restrict__ out)
{
  const int tid = threadIdx.x;  // 256
  float v = per_b[tid];
#pragma unroll
  for (int off = 32; off >= 1; off >>= 1) v += __shfl_xor(v, off, 64);
  __shared__ float s[4];
  if ((tid & 63) == 0) s[tid >> 6] = v;
  __syncthreads();
  if (tid == 0) out[0] = ((s[0] + s[1]) + (s[2] + s[3])) * (1.0f / (float)B_);
}

extern "C" void kernel_launch(void* const* d_in, const int* in_sizes, int n_in,
                              void* d_out, int out_size, void* d_ws, size_t ws_size,
                              hipStream_t stream) {
  const float* em  = (const float*)d_in[0];   // [B,T,K2] f32
  const float* tr  = (const float*)d_in[1];   // [K2,K2]  f32
  const int*   len = (const int*)d_in[2];     // [B] i32
  const int*   lab = (const int*)d_in[3];     // [B,T] i32
  float* out  = (float*)d_out;
  float* ws   = (float*)d_ws;                 // [0..255] per-batch scores
  int*   perm = (int*)(ws + B_);              // [256] length-sorted pairing

  pair_kernel<<<1, 256, 0, stream>>>(len, perm);
  crf_fwd_kernel<<<B_ / 2, 128, 0, stream>>>(em, tr, len, lab, perm, ws);
  reduce_mean_kernel<<<1, 256, 0, stream>>>(ws, out);
}

// Round 8
// 462.148 us; speedup vs baseline: 1.2877x; 1.1459x over previous
//
#include <hip/hip_runtime.h>

// CRF NLL forward loss. B=256, T=2048, K2=52 (50 labels + START=50 + STOP=51).
// Linear-domain bidirectional recurrence, one chain per wave (R9 structure):
//   wave 0 (fwd): v <- E_t * (M v),   t = 0..h-1      (h = L/2)
//   wave 1 (bwd): u <- M^T (E_t * u), t = L-1..h
//   score = ln2*(Cf + Cb + log2(dot(u,v)))
//
// R14 change: R13 proved (a) wall = chain_len x step_cost, so chains must stay
// 1-per-wave (512 chains, 1024 SIMDs — waves are abundant); (b) step = ~330cyc
// issue + ~310cyc stall, the stall being the LDS write->lgkmcnt->read round
// trip used ONLY to broadcast 52 lane-local values. Fix: ds_bpermute_b32 with
// uniform index i*4 broadcasts lane i's VGPR to all lanes — no LDS write, no
// write-wait. 52 bpermutes + 52 FMAs (8 accs) per step; renorm magnitude is
// bpermute result #50 (fwd) / #0 (bwd) — free. No LDS in the loop at all.
// Renorm every 4 steps by an always-positive component (growth < 2^95).

#define B_    256
#define T_    2048
#define K2_   52
#define LOG2E_ 1.4426950408889634f
#define LN2_   0.6931471805599453f

__device__ __forceinline__ int imin(int a, int b) { return a < b ? a : b; }
__device__ __forceinline__ int imax(int a, int b) { return a > b ? a : b; }

#define X2F(e) __builtin_amdgcn_exp2f((e) * LOG2E_)

#define FORALL52(F) \
  F(0) F(1) F(2) F(3) F(4) F(5) F(6) F(7) F(8) F(9) F(10) F(11) F(12) F(13) \
  F(14) F(15) F(16) F(17) F(18) F(19) F(20) F(21) F(22) F(23) F(24) F(25) \
  F(26) F(27) F(28) F(29) F(30) F(31) F(32) F(33) F(34) F(35) F(36) F(37) \
  F(38) F(39) F(40) F(41) F(42) F(43) F(44) F(45) F(46) F(47) F(48) F(49) \
  F(50) F(51)

// i, chain c = i % 8 (8 accumulators -> FMA dep depth 7)
#define FORALL52C(F) \
  F(0,0) F(1,1) F(2,2) F(3,3) F(4,4) F(5,5) F(6,6) F(7,7) \
  F(8,0) F(9,1) F(10,2) F(11,3) F(12,4) F(13,5) F(14,6) F(15,7) \
  F(16,0) F(17,1) F(18,2) F(19,3) F(20,4) F(21,5) F(22,6) F(23,7) \
  F(24,0) F(25,1) F(26,2) F(27,3) F(28,4) F(29,5) F(30,6) F(31,7) \
  F(32,0) F(33,1) F(34,2) F(35,3) F(36,4) F(37,5) F(38,6) F(39,7) \
  F(40,0) F(41,1) F(42,2) F(43,3) F(44,4) F(45,5) F(46,6) F(47,7) \
  F(48,0) F(49,1) F(50,2) F(51,3)

// M defs: volatile asm (unsinkable) so the 52 values stay register-resident.
// Forward: lane n holds row n (MF_i = exp(tr[n][i])). Backward: col n.
#define DECLMF(i) float MF_##i; { float _t = tr[n * K2_ + i] * LOG2E_; \
  asm volatile("v_exp_f32 %0, %1\n\ts_nop 1" : "=v"(MF_##i) : "v"(_t)); }
#define DECLMB(i) float MB_##i; { float _t = tr[i * K2_ + n] * LOG2E_; \
  asm volatile("v_exp_f32 %0, %1\n\ts_nop 1" : "=v"(MB_##i) : "v"(_t)); }

// Broadcast component i of the distributed vector via lane crossbar.
#define DECLB(i,c) \
  float _b##i = __int_as_float(__builtin_amdgcn_ds_bpermute(4 * (i), _srci));

#define ACCF(i,c) _a##c = fmaf(MF_##i, _b##i, _a##c);
#define ACCB(i,c) _a##c = fmaf(MB_##i, _b##i, _a##c);

// y_n = sum_i M[n][i] * src_i  (src distributed one component per lane).
// After this, _b50 / _b0 are available as renorm magnitudes.
#define MATVEC_F(SRC, OUTY) \
    int _srci = __float_as_int(SRC); \
    FORALL52C(DECLB) \
    float _a0=0.f,_a1=0.f,_a2=0.f,_a3=0.f,_a4=0.f,_a5=0.f,_a6=0.f,_a7=0.f; \
    FORALL52C(ACCF) \
    float OUTY = ((_a0+_a1)+(_a2+_a3)) + ((_a4+_a5)+(_a6+_a7));

#define MATVEC_B(SRC, OUTY) \
    int _srci = __float_as_int(SRC); \
    FORALL52C(DECLB) \
    float _a0=0.f,_a1=0.f,_a2=0.f,_a3=0.f,_a4=0.f,_a5=0.f,_a6=0.f,_a7=0.f; \
    FORALL52C(ACCB) \
    float OUTY = ((_a0+_a1)+(_a2+_a3)) + ((_a4+_a5)+(_a6+_a7));

// ---- forward steps: v' = E_t * (M v); renorm comp 50 (START row, >0) -------
#define FSTEP_R(EV, NEWIDX) do {                                \
    float _ne = emb[(size_t)(NEWIDX) * K2_ + n];                \
    MATVEC_F(vv, _y)                                            \
    float _m   = _b50;                                          \
    float _inv = __builtin_amdgcn_rcpf(_m);                     \
    C += __builtin_amdgcn_logf(_m);                             \
    vv = _y * (_inv * X2F(EV));                                 \
    EV = _ne;                                                   \
  } while (0)
#define FSTEP_N(EV, NEWIDX) do {                                \
    float _ne = emb[(size_t)(NEWIDX) * K2_ + n];                \
    MATVEC_F(vv, _y)                                            \
    vv = _y * X2F(EV);                                          \
    EV = _ne;                                                   \
  } while (0)

// ---- backward steps: state vv holds w = E.*u; u' = M^T w; w' = u'*E_next ---
#define BSTEP_R(EV, NEWIDX) do {                                \
    float _ne = emb[(size_t)(NEWIDX) * K2_ + n];                \
    MATVEC_B(vv, _y)                                            \
    float _m   = _b0;                                           \
    float _inv = __builtin_amdgcn_rcpf(_m);                     \
    C += __builtin_amdgcn_logf(_m);                             \
    ub = _y * _inv;                                             \
    vv = ub * X2F(EV);                                          \
    EV = _ne;                                                   \
  } while (0)
#define BSTEP_N(EV, NEWIDX) do {                                \
    float _ne = emb[(size_t)(NEWIDX) * K2_ + n];                \
    MATVEC_B(vv, _y)                                            \
    ub = _y;                                                    \
    vv = ub * X2F(EV);                                          \
    EV = _ne;                                                   \
  } while (0)

__global__ __launch_bounds__(128)
__attribute__((amdgpu_waves_per_eu(1, 1)))
void crf_fwd_kernel(const float* __restrict__ em,
                    const float* __restrict__ tr,
                    const int*  __restrict__ len,
                    const int*  __restrict__ lab,
                    float* __restrict__ per_b)
{
  const int b    = blockIdx.x;
  const int tid  = threadIdx.x;                      // 128 = 2 waves
  const int wave = tid >> 6;
  const int lane = tid & 63;
  const int n    = (lane < K2_) ? lane : (K2_ - 1);  // lanes 52..63 mirror 51
  const int L    = len[b];
  const int h    = L >> 1;                           // fwd steps; bwd L-h
  const float* emb = em + (size_t)b * (T_ * K2_);

  __shared__ float sU[64];     // backward wave's final u (handoff only)
  __shared__ float sCb[1];     // backward wave's log-offset
  __shared__ float sG[2];      // per-wave gold partials

  float vv, C = 0.0f;

  if (wave == 0) {
    // ---------------- forward half: h steps, rows 0..h-1 ----------------
    FORALL52(DECLMF)
    vv = (lane == 50) ? 1.0f : 0.0f;
    float e0 = emb[0 * K2_ + n];
    float e1 = emb[1 * K2_ + n];
    float e2 = emb[2 * K2_ + n];
    float e3 = emb[3 * K2_ + n];
    int t = 0;
    for (; t + 4 <= h; t += 4) {
      int i4 = imin(t + 4, T_ - 1), i5 = imin(t + 5, T_ - 1);
      int i6 = imin(t + 6, T_ - 1), i7 = imin(t + 7, T_ - 1);
      FSTEP_R(e0, i4);
      FSTEP_N(e1, i5);
      FSTEP_N(e2, i6);
      FSTEP_N(e3, i7);
    }
    int rem = h - t;
    if (rem > 0) FSTEP_R(e0, T_ - 1);
    if (rem > 1) FSTEP_N(e1, T_ - 1);
    if (rem > 2) FSTEP_N(e2, T_ - 1);
  } else {
    // ---------------- backward half: L-h steps, rows L-1 down to h ------
    FORALL52(DECLMB)
    float ub = X2F(tr[(K2_ - 1) * K2_ + n]);              // u_0 = s (STOP row)
    int cnt = L - h;
    float e0 = emb[(size_t)(L - 1) * K2_ + n];            // E for first step
    float eA = emb[(size_t)imax(L - 2, 0) * K2_ + n];     // next-E, step 1
    float eB = emb[(size_t)imax(L - 3, 0) * K2_ + n];     // next-E, step 2
    float eC = emb[(size_t)imax(L - 4, 0) * K2_ + n];     // next-E, step 3
    float eD = emb[(size_t)imax(L - 5, 0) * K2_ + n];     // next-E, step 4
    vv = ub * X2F(e0);                                    // w_0 = E_{L-1}.*u_0
    int s = 0;
    for (; s + 4 <= cnt; s += 4) {
      int j4 = imax(L - 6 - s, 0), j5 = imax(L - 7 - s, 0);
      int j6 = imax(L - 8 - s, 0), j7 = imax(L - 9 - s, 0);
      BSTEP_R(eA, j4);
      BSTEP_N(eB, j5);
      BSTEP_N(eC, j6);
      BSTEP_N(eD, j7);
    }
    int rem = cnt - s;
    if (rem > 0) BSTEP_R(eA, 0);
    if (rem > 1) BSTEP_N(eB, 0);
    if (rem > 2) BSTEP_N(eC, 0);

    sU[lane] = ub;              // publish final u
    if (lane == 0) sCb[0] = C;
  }

  // ---- gold score (both waves, stride 128) ----
  float gold = 0.0f;
  const int* labb = lab + b * T_;
  for (int tt = tid; tt < L; tt += 128) {
    int l1 = labb[tt];
    int l0 = (tt == 0) ? 50 : labb[tt - 1];
    gold += emb[(size_t)tt * K2_ + l1] + tr[l1 * K2_ + l0];
  }
  if (tid == 0) gold += tr[(K2_ - 1) * K2_ + labb[L - 1]];  // STOP <- last label
#pragma unroll
  for (int off = 32; off >= 1; off >>= 1)
    gold += __shfl_xor(gold, off, 64);
  if (lane == 0) sG[wave] = gold;

  __syncthreads();

  if (wave == 0) {
    // dot(u, v) + combine log-offsets
    float x = (lane < K2_) ? vv * sU[lane] : 0.0f;
#pragma unroll
    for (int off = 32; off >= 1; off >>= 1)
      x += __shfl_xor(x, off, 64);
    float fwd = (C + sCb[0] + __builtin_amdgcn_logf(x)) * LN2_;
    if (lane == 0) per_b[b] = fwd - (sG[0] + sG[1]);
  }
}

__global__ void reduce_mean_kernel(const float* __restrict__ per_b,
                                   float* __restrict__ out)
{
  const int tid = threadIdx.x;  // 256
  float v = per_b[tid];
#pragma unroll
  for (int off = 32; off >= 1; off >>= 1) v += __shfl_xor(v, off, 64);
  __shared__ float s[4];
  if ((tid & 63) == 0) s[tid >> 6] = v;
  __syncthreads();
  if (tid == 0) out[0] = ((s[0] + s[1]) + (s[2] + s[3])) * (1.0f / (float)B_);
}

extern "C" void kernel_launch(void* const* d_in, const int* in_sizes, int n_in,
                              void* d_out, int out_size, void* d_ws, size_t ws_size,
                              hipStream_t stream) {
  const float* em  = (const float*)d_in[0];   // [B,T,K2] f32
  const float* tr  = (const float*)d_in[1];   // [K2,K2]  f32
  const int*   len = (const int*)d_in[2];     // [B] i32
  const int*   lab = (const int*)d_in[3];     // [B,T] i32
  float* out = (float*)d_out;
  float* ws  = (float*)d_ws;                  // 256 floats of per-batch scores

  crf_fwd_kernel<<<B_, 128, 0, stream>>>(em, tr, len, lab, ws);
  reduce_mean_kernel<<<1, 256, 0, stream>>>(ws, out);
}